// Round 3
// baseline (58115.881 us; speedup 1.0000x reference)
//
#include <hip/hip_runtime.h>
#include <hip/hip_fp16.h>

// MC-LSTM persistent recurrence, v3: 49 WGs (48 unit-WGs + 1 o-WG).
// Non-atomic two-phase slab reduction (agent-scope relaxed stores), two
// counter barriers per step; x-part GEMM overlapped with the barrier wait.

#define TT 2048
#define NWG 49
#define NRED 48

typedef _Float16 f16;
typedef _Float16 f16x8 __attribute__((ext_vector_type(8)));
typedef _Float16 f16x4 __attribute__((ext_vector_type(4)));
typedef float f32x4 __attribute__((ext_vector_type(4)));
typedef float f32x2 __attribute__((ext_vector_type(2)));

#define LD_RLX(p)   __hip_atomic_load((p), __ATOMIC_RELAXED, __HIP_MEMORY_SCOPE_AGENT)
#define LD_ACQ(p)   __hip_atomic_load((p), __ATOMIC_ACQUIRE, __HIP_MEMORY_SCOPE_AGENT)
#define ST_RLX(p,v) __hip_atomic_store((p), (v), __ATOMIC_RELAXED, __HIP_MEMORY_SCOPE_AGENT)

// ---- ws layout (bytes) ----
#define OFF_WH   0u
#define SZ_WH    (97u * 8192u * 2u)
#define OFF_PART ((OFF_WH + SZ_WH + 255u) & ~255u)   // 48 x [128][64] f32 partials
#define SZ_PART  (48u * 8192u * 4u)
#define OFF_CB   (OFF_PART + SZ_PART)                // [128][64] f32 c state
#define SZ_CB    (8192u * 4u)
#define OFF_OB   (OFF_CB + SZ_CB)                    // [128][64] f32 o gate
#define SZ_OB    (8192u * 4u)
#define OFF_NS   (OFF_OB + SZ_OB)                    // 48 f32 norm partials
#define SZ_NS    256u
#define OFF_CTRA (OFF_NS + SZ_NS)
#define OFF_CTRB (OFF_CTRA + TT * 4u)
#define ZERO_OFF OFF_CTRA
#define ZERO_LEN (2u * TT * 4u)

__global__ void prep_kernel(const float* __restrict__ Wi, const float* __restrict__ Wr,
                            const float* __restrict__ Wo, f16* __restrict__ Wh) {
  int idx = blockIdx.x * 256 + threadIdx.x;
  if (idx >= 97 * 8192) return;
  int g = idx & 127, h = (idx >> 7) & 63, r = idx >> 13;
  float v;
  if (r < 32)      v = Wi[g * 2048 + r * 64 + h];
  else if (r < 96) v = Wr[g * 4096 + (r - 32) * 64 + h];
  else             v = Wo[g * 64 + h];
  Wh[idx] = (f16)v;
}

__launch_bounds__(256, 1)
__global__ void mclstm_kernel(const float* __restrict__ xm, const float* __restrict__ xa,
                              const float* __restrict__ bi, const float* __restrict__ br,
                              const float* __restrict__ bo, const f16* __restrict__ Wh,
                              float* __restrict__ part, float* __restrict__ cbuf,
                              float* __restrict__ obuf, float* __restrict__ nslab,
                              unsigned* __restrict__ ctrA, unsigned* __restrict__ ctrB,
                              float* __restrict__ out) {
  const int j = blockIdx.x, tid = threadIdx.x;
  const int w = tid >> 6, l = tid & 63, lr = l & 15, lk = l >> 4;
  const bool isO = (j == NRED);

  __shared__ __align__(16) f16 featX[128][72];  // [b][g0..63], wave-private rows
  __shared__ float cL[128][66];                 // staged c (raw f32)
  __shared__ float nsl[NRED];
  __shared__ float nred[4];

  for (int e = tid; e < 128 * 66; e += 256) ((float*)cL)[e] = 0.f;

  // ---- persistent weights in registers; o-WG duplicates its unit ----
  f16x8 Bf[2][4][4];
  float bu[2][4];
#pragma unroll
  for (int un = 0; un < 2; ++un) {
    int u = isO ? 96 : j * 2 + un;
#pragma unroll
    for (int ht = 0; ht < 4; ++ht) {
      int col = ht * 16 + lr;
      bu[un][ht] = isO ? bo[col] : ((u < 32) ? bi[u * 64 + col] : br[(u - 32) * 64 + col]);
#pragma unroll
      for (int kk = 0; kk < 4; ++kk)
        Bf[un][ht][kk] = *(const f16x8*)(Wh + (size_t)u * 8192 + col * 128 + kk * 32 + lk * 8);
    }
  }
  __syncthreads();

  // prefetch x for t=0
  float4 xmr[4], xar[4];
  {
    const float4* x4 = (const float4*)xm;
    const float4* a4 = (const float4*)xa;
#pragma unroll
    for (int k = 0; k < 4; ++k) {
      int idx4 = w * 256 + k * 64 + l;
      xmr[k] = x4[idx4];
      xar[k] = a4[idx4];
    }
  }

  for (int t = 0; t < TT; ++t) {
    // ---- 1. featX build (wave-private rows) ----
#pragma unroll
    for (int k = 0; k < 4; ++k) {
      int idx4 = w * 256 + k * 64 + l;
      int row = idx4 >> 3, cq = (idx4 & 7) * 4;
      float4 v = xmr[k];
      *(f16x4*)&featX[row][cq] = (f16x4){(f16)v.x, (f16)v.y, (f16)v.z, (f16)v.w};
      float4 va = xar[k];
      *(f16x4*)&featX[row][32 + cq] = (f16x4){(f16)va.x, (f16)va.y, (f16)va.z, (f16)va.w};
    }

    // ---- 2. x-part GEMM (kk=0,1) — independent of c, overlaps barrier wait ----
    f32x4 acc[2][2][4];
#pragma unroll
    for (int un = 0; un < 2; ++un)
#pragma unroll
      for (int bt = 0; bt < 2; ++bt)
#pragma unroll
        for (int ht = 0; ht < 4; ++ht) acc[un][bt][ht] = (f32x4){0.f, 0.f, 0.f, 0.f};
#pragma unroll
    for (int bt = 0; bt < 2; ++bt) {
      int row = (2 * w + bt) * 16 + lr;
      f16x8 A0 = *(const f16x8*)&featX[row][lk * 8];
      f16x8 A1 = *(const f16x8*)&featX[row][32 + lk * 8];
#pragma unroll
      for (int un = 0; un < 2; ++un)
#pragma unroll
        for (int ht = 0; ht < 4; ++ht) {
          acc[un][bt][ht] = __builtin_amdgcn_mfma_f32_16x16x32_f16(A0, Bf[un][ht][0],
                                                                   acc[un][bt][ht], 0, 0, 0);
          acc[un][bt][ht] = __builtin_amdgcn_mfma_f32_16x16x32_f16(A1, Bf[un][ht][1],
                                                                   acc[un][bt][ht], 0, 0, 0);
        }
    }

    // ---- 3. wait for c[t], stage it, compute inv norm ----
    float inv;
    if (t > 0) {
      if (tid == 0)
        while (LD_ACQ(&ctrB[t - 1]) < (unsigned)NWG) __builtin_amdgcn_s_sleep(1);
      __syncthreads();
#pragma unroll 8
      for (int k = 0; k < 32; ++k) {
        int i = tid + k * 256;
        cL[i >> 6][i & 63] = LD_RLX(&cbuf[i]);
      }
      if (tid < NRED) nsl[tid] = LD_RLX(&nslab[tid]);
      __syncthreads();
      float nm = 0.f;
#pragma unroll
      for (int p = 0; p < NRED; ++p) nm += nsl[p];
      inv = __builtin_amdgcn_rcpf(nm + 1e-5f);
    } else {
      inv = 0.f;  // c==0 -> cn==0
    }

    // ---- 4. prefetch x[t+1] ----
    if (t + 1 < TT) {
      const float4* x4 = (const float4*)(xm + (size_t)(t + 1) * 4096);
      const float4* a4 = (const float4*)(xa + (size_t)(t + 1) * 4096);
#pragma unroll
      for (int k = 0; k < 4; ++k) {
        int idx4 = w * 256 + k * 64 + l;
        xmr[k] = x4[idx4];
        xar[k] = a4[idx4];
      }
    }

    // ---- 5. c-part GEMM (kk=2,3) ----
#pragma unroll
    for (int bt = 0; bt < 2; ++bt) {
      int row = (2 * w + bt) * 16 + lr;
      f16x8 A23[2];
#pragma unroll
      for (int kk = 0; kk < 2; ++kk) {
        int h0 = kk * 32 + lk * 8;
        f16x8 af;
#pragma unroll
        for (int i2 = 0; i2 < 4; ++i2) {
          f32x2 c2 = *(const f32x2*)&cL[row][h0 + i2 * 2];
          af[i2 * 2]     = (f16)(c2.x * inv);
          af[i2 * 2 + 1] = (f16)(c2.y * inv);
        }
        A23[kk] = af;
      }
#pragma unroll
      for (int un = 0; un < 2; ++un)
#pragma unroll
        for (int ht = 0; ht < 4; ++ht) {
          acc[un][bt][ht] = __builtin_amdgcn_mfma_f32_16x16x32_f16(A23[0], Bf[un][ht][2],
                                                                   acc[un][bt][ht], 0, 0, 0);
          acc[un][bt][ht] = __builtin_amdgcn_mfma_f32_16x16x32_f16(A23[1], Bf[un][ht][3],
                                                                   acc[un][bt][ht], 0, 0, 0);
        }
    }

    // ---- 6. epilogue ----
    if (!isO) {
      const float* xmtp = xm + (size_t)t * 4096;
      float contrib[2][4][4];
#pragma unroll
      for (int bt = 0; bt < 2; ++bt)
#pragma unroll
        for (int ht = 0; ht < 4; ++ht)
#pragma unroll
          for (int rr = 0; rr < 4; ++rr) contrib[bt][ht][rr] = 0.f;
#pragma unroll
      for (int un = 0; un < 2; ++un) {
        int u = j * 2 + un;
        bool isI = (u < 32);
        int kidx = isI ? u : u - 32;
#pragma unroll
        for (int bt = 0; bt < 2; ++bt)
#pragma unroll
          for (int rr = 0; rr < 4; ++rr) {
            int b = (2 * w + bt) * 16 + lk * 4 + rr;
            float s4[4], sum = 0.f;
#pragma unroll
            for (int ht = 0; ht < 4; ++ht) {
              float z = acc[un][bt][ht][rr] + bu[un][ht];
              float sg = __builtin_amdgcn_rcpf(1.0f + __expf(-z));
              s4[ht] = sg;
              sum += sg;
            }
            float r4 = sum;
            r4 += __shfl_xor(r4, 1, 64);
            r4 += __shfl_xor(r4, 2, 64);
            r4 += __shfl_xor(r4, 4, 64);
            r4 += __shfl_xor(r4, 8, 64);
            float wr = isI ? xmtp[b * 32 + u] : cL[b][kidx];
            float sc = wr * __builtin_amdgcn_rcpf(fmaxf(r4, 1e-12f));
#pragma unroll
            for (int ht = 0; ht < 4; ++ht) contrib[bt][ht][rr] += s4[ht] * sc;
          }
      }
#pragma unroll
      for (int bt = 0; bt < 2; ++bt)
#pragma unroll
        for (int ht = 0; ht < 4; ++ht)
#pragma unroll
          for (int rr = 0; rr < 4; ++rr) {
            int b = (2 * w + bt) * 16 + lk * 4 + rr, h = ht * 16 + lr;
            ST_RLX(&part[j * 8192 + b * 64 + h], contrib[bt][ht][rr]);
          }
    } else {
#pragma unroll
      for (int bt = 0; bt < 2; ++bt)
#pragma unroll
        for (int ht = 0; ht < 4; ++ht)
#pragma unroll
          for (int rr = 0; rr < 4; ++rr) {
            float z = acc[0][bt][ht][rr] + bu[0][ht];
            float sg = __builtin_amdgcn_rcpf(1.0f + __expf(-z));
            int b = (2 * w + bt) * 16 + lk * 4 + rr, h = ht * 16 + lr;
            ST_RLX(&obuf[b * 64 + h], sg);
          }
    }

    // ---- 7. barrier A (syncthreads drains vmcnt before release) ----
    __syncthreads();
    if (tid == 0)
      __hip_atomic_fetch_add(&ctrA[t], 1u, __ATOMIC_RELEASE, __HIP_MEMORY_SCOPE_AGENT);

    // ---- 8/9. phase B: distributed reduce + state update ----
    if (tid == 0)
      while (LD_ACQ(&ctrA[t]) < (unsigned)NWG) __builtin_amdgcn_s_sleep(1);
    __syncthreads();

    float ns = 0.f;
    int e = j * 171 + tid;
    if (j < NRED && tid < 171 && e < 8192) {
      float vv[NRED];
#pragma unroll
      for (int p = 0; p < NRED; ++p) vv[p] = LD_RLX(&part[p * 8192 + e]);
      float mn = 0.f;
#pragma unroll
      for (int p = 0; p < NRED; ++p) mn += vv[p];
      float ov = LD_RLX(&obuf[e]);
      float cn_ = (1.0f - ov) * mn;
      out[(size_t)t * 8192 + e] = ov * mn;
      out[(size_t)(TT + t) * 8192 + e] = cn_;
      ST_RLX(&cbuf[e], cn_);
      ns = fabsf(cn_);
    }
    ns += __shfl_xor(ns, 1, 64);
    ns += __shfl_xor(ns, 2, 64);
    ns += __shfl_xor(ns, 4, 64);
    ns += __shfl_xor(ns, 8, 64);
    ns += __shfl_xor(ns, 16, 64);
    ns += __shfl_xor(ns, 32, 64);
    if (l == 0) nred[w] = ns;
    __syncthreads();
    if (tid == 0) {
      if (j < NRED) ST_RLX(&nslab[j], nred[0] + nred[1] + nred[2] + nred[3]);
      __hip_atomic_fetch_add(&ctrB[t], 1u, __ATOMIC_RELEASE, __HIP_MEMORY_SCOPE_AGENT);
    }
  }
}

extern "C" void kernel_launch(void* const* d_in, const int* in_sizes, int n_in,
                              void* d_out, int out_size, void* d_ws, size_t ws_size,
                              hipStream_t stream) {
  (void)in_sizes; (void)n_in; (void)out_size; (void)ws_size;
  const float* xm = (const float*)d_in[0];
  const float* xa = (const float*)d_in[1];
  const float* Wi = (const float*)d_in[2];
  const float* bi = (const float*)d_in[3];
  const float* Wr = (const float*)d_in[4];
  const float* br = (const float*)d_in[5];
  const float* Wo = (const float*)d_in[6];
  const float* bo = (const float*)d_in[7];

  char* ws = (char*)d_ws;
  f16* Wh        = (f16*)(ws + OFF_WH);
  float* part    = (float*)(ws + OFF_PART);
  float* cbuf    = (float*)(ws + OFF_CB);
  float* obuf    = (float*)(ws + OFF_OB);
  float* nslab   = (float*)(ws + OFF_NS);
  unsigned* ctrA = (unsigned*)(ws + OFF_CTRA);
  unsigned* ctrB = (unsigned*)(ws + OFF_CTRB);

  hipMemsetAsync(ws + ZERO_OFF, 0, ZERO_LEN, stream);
  prep_kernel<<<(97 * 8192 + 255) / 256, 256, 0, stream>>>(Wi, Wr, Wo, Wh);
  mclstm_kernel<<<NWG, 256, 0, stream>>>(xm, xa, bi, br, bo, Wh, part, cbuf, obuf,
                                         nslab, ctrA, ctrB, (float*)d_out);
}

// Round 5
// 51450.842 us; speedup vs baseline: 1.1295x; 1.1295x over previous
//
#include <hip/hip_runtime.h>
#include <hip/hip_fp16.h>

// MC-LSTM persistent recurrence, v4b: 49 WGs (48 unit-WGs + 1 o-WG).
// Two-phase fp16 slab reduction, per-step counters padded to own cachelines,
// x-GEMM(t+1) pipelined into the ctrA straggler window. (v4 + f16x2 typedef fix)

#define TT 2048
#define NWG 49
#define NRED 48
#define CTRS 32  // u32 stride between per-step counters (128 B line)

typedef _Float16 f16;
typedef _Float16 f16x8 __attribute__((ext_vector_type(8)));
typedef _Float16 f16x4 __attribute__((ext_vector_type(4)));
typedef _Float16 f16x2 __attribute__((ext_vector_type(2)));
typedef float f32x4 __attribute__((ext_vector_type(4)));

#define LD_RLX(p)   __hip_atomic_load((p), __ATOMIC_RELAXED, __HIP_MEMORY_SCOPE_AGENT)
#define LD_ACQ(p)   __hip_atomic_load((p), __ATOMIC_ACQUIRE, __HIP_MEMORY_SCOPE_AGENT)
#define ST_RLX(p,v) __hip_atomic_store((p), (v), __ATOMIC_RELAXED, __HIP_MEMORY_SCOPE_AGENT)

static __device__ __forceinline__ void stf16(f16* p, float v) {
  f16 h = (f16)v;
  unsigned short u;
  __builtin_memcpy(&u, &h, 2);
  __hip_atomic_store((unsigned short*)p, u, __ATOMIC_RELAXED, __HIP_MEMORY_SCOPE_AGENT);
}

// ---- ws layout (bytes) ----
#define OFF_WH   0u
#define SZ_WH    (97u * 8192u * 2u)
#define OFF_PART ((OFF_WH + SZ_WH + 255u) & ~255u)   // 48 x [128][64] fp16 partials
#define SZ_PART  (48u * 8192u * 2u)
#define OFF_CB   (OFF_PART + SZ_PART)                // [128][64] fp16 c state
#define SZ_CB    (8192u * 2u)
#define OFF_OB   (OFF_CB + SZ_CB)                    // [128][64] f32 o gate
#define SZ_OB    (8192u * 4u)
#define OFF_NS   (OFF_OB + SZ_OB)                    // 48 f32 norm partials
#define SZ_NS    256u
#define OFF_CTRA ((OFF_NS + SZ_NS + 255u) & ~255u)   // padded counters
#define SZ_CTR   (TT * 128u)
#define OFF_CTRB (OFF_CTRA + SZ_CTR)
#define ZERO_OFF OFF_CTRA
#define ZERO_LEN (2u * SZ_CTR)

__global__ void prep_kernel(const float* __restrict__ Wi, const float* __restrict__ Wr,
                            const float* __restrict__ Wo, f16* __restrict__ Wh) {
  int idx = blockIdx.x * 256 + threadIdx.x;
  if (idx >= 97 * 8192) return;
  int g = idx & 127, h = (idx >> 7) & 63, r = idx >> 13;
  float v;
  if (r < 32)      v = Wi[g * 2048 + r * 64 + h];
  else if (r < 96) v = Wr[g * 4096 + (r - 32) * 64 + h];
  else             v = Wo[g * 64 + h];
  Wh[idx] = (f16)v;
}

__launch_bounds__(256, 1)
__global__ void mclstm_kernel(const float* __restrict__ xm, const float* __restrict__ xa,
                              const float* __restrict__ bi, const float* __restrict__ br,
                              const float* __restrict__ bo, const f16* __restrict__ Wh,
                              f16* __restrict__ part16, f16* __restrict__ cbuf16,
                              float* __restrict__ obuf, float* __restrict__ nslab,
                              unsigned* __restrict__ ctrA, unsigned* __restrict__ ctrB,
                              float* __restrict__ out) {
  const int j = blockIdx.x, tid = threadIdx.x;
  const int w = tid >> 6, l = tid & 63, lr = l & 15, lk = l >> 4;
  const bool isO = (j == NRED);

  __shared__ __align__(16) f16 featX[2][128][136];  // [buf][b][g]; rows 272B
  __shared__ __align__(4) f16 cL16[128][66];        // raw c (fp16)
  __shared__ float nsl[NRED];
  __shared__ float nred[4];

  // zero c state + featX[0] c-cols (t=0 path reads them)
  for (int i = tid; i < 128 * 33; i += 256) ((unsigned*)cL16)[i] = 0u;
  for (int p = tid; p < 4096; p += 256) {
    int b = p >> 5, hp = (p & 31) * 2;
    *(unsigned*)&featX[0][b][64 + hp] = 0u;
  }

  // ---- persistent weights in registers; o-WG duplicates unit 96 ----
  f16x8 Bf[2][4][4];
  float bu[2][4];
#pragma unroll
  for (int un = 0; un < 2; ++un) {
    int u = isO ? 96 : j * 2 + un;
#pragma unroll
    for (int ht = 0; ht < 4; ++ht) {
      int col = ht * 16 + lr;
      bu[un][ht] = isO ? bo[col] : ((u < 32) ? bi[u * 64 + col] : br[(u - 32) * 64 + col]);
#pragma unroll
      for (int kk = 0; kk < 4; ++kk)
        Bf[un][ht][kk] = *(const f16x8*)(Wh + (size_t)u * 8192 + col * 128 + kk * 32 + lk * 8);
    }
  }

  float4 xmr[4], xar[4];
  {
    const float4* x4 = (const float4*)xm;
    const float4* a4 = (const float4*)xa;
#pragma unroll
    for (int k = 0; k < 4; ++k) {
      int idx4 = w * 256 + k * 64 + l;
      xmr[k] = x4[idx4];
      xar[k] = a4[idx4];
    }
  }
  __syncthreads();

  // pre-loop: build featX[0] x-cols (wave-private) + x-GEMM(0)
  f32x4 acc[2][2][4];
#pragma unroll
  for (int k = 0; k < 4; ++k) {
    int idx4 = w * 256 + k * 64 + l;
    int row = idx4 >> 3, cq = (idx4 & 7) * 4;
    float4 v = xmr[k];
    *(f16x4*)&featX[0][row][cq] = (f16x4){(f16)v.x, (f16)v.y, (f16)v.z, (f16)v.w};
    float4 va = xar[k];
    *(f16x4*)&featX[0][row][32 + cq] = (f16x4){(f16)va.x, (f16)va.y, (f16)va.z, (f16)va.w};
  }
#pragma unroll
  for (int un = 0; un < 2; ++un)
#pragma unroll
    for (int bt = 0; bt < 2; ++bt)
#pragma unroll
      for (int ht = 0; ht < 4; ++ht) acc[un][bt][ht] = (f32x4){0.f, 0.f, 0.f, 0.f};
#pragma unroll
  for (int bt = 0; bt < 2; ++bt) {
    int row = (2 * w + bt) * 16 + lr;
    f16x8 A0 = *(const f16x8*)&featX[0][row][lk * 8];
    f16x8 A1 = *(const f16x8*)&featX[0][row][32 + lk * 8];
#pragma unroll
    for (int un = 0; un < 2; ++un)
#pragma unroll
      for (int ht = 0; ht < 4; ++ht) {
        acc[un][bt][ht] = __builtin_amdgcn_mfma_f32_16x16x32_f16(A0, Bf[un][ht][0],
                                                                 acc[un][bt][ht], 0, 0, 0);
        acc[un][bt][ht] = __builtin_amdgcn_mfma_f32_16x16x32_f16(A1, Bf[un][ht][1],
                                                                 acc[un][bt][ht], 0, 0, 0);
      }
  }

  for (int t = 0; t < TT; ++t) {
    const int buf = t & 1;

    // ---- (a) issue x[t+1] prefetch (regs stay in flight through the poll) ----
    if (t + 1 < TT) {
      const float4* x4 = (const float4*)(xm + (size_t)(t + 1) * 4096);
      const float4* a4 = (const float4*)(xa + (size_t)(t + 1) * 4096);
#pragma unroll
      for (int k = 0; k < 4; ++k) {
        int idx4 = w * 256 + k * 64 + l;
        xmr[k] = x4[idx4];
        xar[k] = a4[idx4];
      }
    }

    // ---- (b) wait for c[t]; stage cn into featX + raw c into cL16 ----
    if (t > 0) {
      if (tid == 0)
        while (LD_ACQ(&ctrB[(t - 1) * CTRS]) < (unsigned)NWG) __builtin_amdgcn_s_sleep(1);
      __syncthreads();
      if (tid < NRED) nsl[tid] = LD_RLX(&nslab[tid]);
      __syncthreads();
      float nm = 0.f;
#pragma unroll
      for (int p = 0; p < NRED; ++p) nm += nsl[p];
      const float inv = __builtin_amdgcn_rcpf(nm + 1e-5f);

      unsigned cv[16];
#pragma unroll
      for (int k = 0; k < 16; ++k)
        cv[k] = LD_RLX((const unsigned*)cbuf16 + tid + k * 256);
#pragma unroll
      for (int k = 0; k < 16; ++k) {
        int p = tid + k * 256;
        int b = p >> 5, hp = (p & 31) * 2;
        f16 c0, c1;
        unsigned short u0 = (unsigned short)(cv[k] & 0xffffu);
        unsigned short u1 = (unsigned short)(cv[k] >> 16);
        __builtin_memcpy(&c0, &u0, 2);
        __builtin_memcpy(&c1, &u1, 2);
        float f0 = (float)c0, f1 = (float)c1;
        *(f16x2*)&featX[buf][b][64 + hp] = (f16x2){(f16)(f0 * inv), (f16)(f1 * inv)};
        *(unsigned*)&cL16[b][hp] = cv[k];
      }
      __syncthreads();
    }

    // ---- (c) c-part GEMM + epilogue + partial stores ----
#pragma unroll
    for (int bt = 0; bt < 2; ++bt) {
      int row = (2 * w + bt) * 16 + lr;
      f16x8 A2 = *(const f16x8*)&featX[buf][row][64 + lk * 8];
      f16x8 A3 = *(const f16x8*)&featX[buf][row][96 + lk * 8];
#pragma unroll
      for (int un = 0; un < 2; ++un)
#pragma unroll
        for (int ht = 0; ht < 4; ++ht) {
          acc[un][bt][ht] = __builtin_amdgcn_mfma_f32_16x16x32_f16(A2, Bf[un][ht][2],
                                                                   acc[un][bt][ht], 0, 0, 0);
          acc[un][bt][ht] = __builtin_amdgcn_mfma_f32_16x16x32_f16(A3, Bf[un][ht][3],
                                                                   acc[un][bt][ht], 0, 0, 0);
        }
    }

    if (!isO) {
      const float* xmtp = xm + (size_t)t * 4096;
      float contrib[2][4][4];
#pragma unroll
      for (int bt = 0; bt < 2; ++bt)
#pragma unroll
        for (int ht = 0; ht < 4; ++ht)
#pragma unroll
          for (int rr = 0; rr < 4; ++rr) contrib[bt][ht][rr] = 0.f;
#pragma unroll
      for (int un = 0; un < 2; ++un) {
        int u = j * 2 + un;
        bool isI = (u < 32);
        int kidx = isI ? u : u - 32;
#pragma unroll
        for (int bt = 0; bt < 2; ++bt)
#pragma unroll
          for (int rr = 0; rr < 4; ++rr) {
            int b = (2 * w + bt) * 16 + lk * 4 + rr;
            float s4[4], sum = 0.f;
#pragma unroll
            for (int ht = 0; ht < 4; ++ht) {
              float z = acc[un][bt][ht][rr] + bu[un][ht];
              float sg = __builtin_amdgcn_rcpf(1.0f + __expf(-z));
              s4[ht] = sg;
              sum += sg;
            }
            float r4 = sum;
            r4 += __shfl_xor(r4, 1, 64);
            r4 += __shfl_xor(r4, 2, 64);
            r4 += __shfl_xor(r4, 4, 64);
            r4 += __shfl_xor(r4, 8, 64);
            float wr;
            if (isI) {
              wr = xmtp[b * 32 + u];
            } else {
              f16 ch = cL16[b][kidx];
              wr = (float)ch;
            }
            float sc = wr * __builtin_amdgcn_rcpf(fmaxf(r4, 1e-12f));
#pragma unroll
            for (int ht = 0; ht < 4; ++ht) contrib[bt][ht][rr] += s4[ht] * sc;
          }
      }
#pragma unroll
      for (int bt = 0; bt < 2; ++bt)
#pragma unroll
        for (int ht = 0; ht < 4; ++ht)
#pragma unroll
          for (int rr = 0; rr < 4; ++rr) {
            int b = (2 * w + bt) * 16 + lk * 4 + rr, h = ht * 16 + lr;
            stf16(&part16[j * 8192 + b * 64 + h], contrib[bt][ht][rr]);
          }
    } else {
#pragma unroll
      for (int bt = 0; bt < 2; ++bt)
#pragma unroll
        for (int ht = 0; ht < 4; ++ht)
#pragma unroll
          for (int rr = 0; rr < 4; ++rr) {
            float z = acc[0][bt][ht][rr] + bu[0][ht];
            float sg = __builtin_amdgcn_rcpf(1.0f + __expf(-z));
            int b = (2 * w + bt) * 16 + lk * 4 + rr, h = ht * 16 + lr;
            ST_RLX(&obuf[b * 64 + h], sg);
          }
    }

    // ---- (d) signal partials ready ----
    __syncthreads();  // drains vmcnt before the release
    if (tid == 0)
      __hip_atomic_fetch_add(&ctrA[t * CTRS], 1u, __ATOMIC_RELEASE, __HIP_MEMORY_SCOPE_AGENT);

    // ---- (e) overlap: build featX[t+1] x-cols + x-GEMM(t+1) ----
    if (t + 1 < TT) {
      const int nbuf = buf ^ 1;
#pragma unroll
      for (int k = 0; k < 4; ++k) {
        int idx4 = w * 256 + k * 64 + l;
        int row = idx4 >> 3, cq = (idx4 & 7) * 4;
        float4 v = xmr[k];
        *(f16x4*)&featX[nbuf][row][cq] = (f16x4){(f16)v.x, (f16)v.y, (f16)v.z, (f16)v.w};
        float4 va = xar[k];
        *(f16x4*)&featX[nbuf][row][32 + cq] =
            (f16x4){(f16)va.x, (f16)va.y, (f16)va.z, (f16)va.w};
      }
#pragma unroll
      for (int un = 0; un < 2; ++un)
#pragma unroll
        for (int bt = 0; bt < 2; ++bt)
#pragma unroll
          for (int ht = 0; ht < 4; ++ht) acc[un][bt][ht] = (f32x4){0.f, 0.f, 0.f, 0.f};
#pragma unroll
      for (int bt = 0; bt < 2; ++bt) {
        int row = (2 * w + bt) * 16 + lr;
        f16x8 A0 = *(const f16x8*)&featX[nbuf][row][lk * 8];
        f16x8 A1 = *(const f16x8*)&featX[nbuf][row][32 + lk * 8];
#pragma unroll
        for (int un = 0; un < 2; ++un)
#pragma unroll
          for (int ht = 0; ht < 4; ++ht) {
            acc[un][bt][ht] = __builtin_amdgcn_mfma_f32_16x16x32_f16(A0, Bf[un][ht][0],
                                                                     acc[un][bt][ht], 0, 0, 0);
            acc[un][bt][ht] = __builtin_amdgcn_mfma_f32_16x16x32_f16(A1, Bf[un][ht][1],
                                                                     acc[un][bt][ht], 0, 0, 0);
          }
      }
    }

    // ---- (f) wait for all partials ----
    if (tid == 0)
      while (LD_ACQ(&ctrA[t * CTRS]) < (unsigned)NWG) __builtin_amdgcn_s_sleep(1);
    __syncthreads();

    // ---- (g) phase B: slice reduce + outputs + c_new ----
    float ns = 0.f;
    int e = j * 171 + tid;
    if (j < NRED && tid < 171 && e < 8192) {
      unsigned short us[NRED];
#pragma unroll
      for (int p = 0; p < NRED; ++p)
        us[p] = __hip_atomic_load((const unsigned short*)part16 + p * 8192 + e,
                                  __ATOMIC_RELAXED, __HIP_MEMORY_SCOPE_AGENT);
      float mn = 0.f;
#pragma unroll
      for (int p = 0; p < NRED; ++p) {
        f16 h;
        __builtin_memcpy(&h, &us[p], 2);
        mn += (float)h;
      }
      float ov = LD_RLX(&obuf[e]);
      float cn_ = (1.0f - ov) * mn;
      out[(size_t)t * 8192 + e] = ov * mn;
      out[(size_t)(TT + t) * 8192 + e] = cn_;
      stf16(&cbuf16[e], cn_);
      ns = fabsf(cn_);
    }
    ns += __shfl_xor(ns, 1, 64);
    ns += __shfl_xor(ns, 2, 64);
    ns += __shfl_xor(ns, 4, 64);
    ns += __shfl_xor(ns, 8, 64);
    ns += __shfl_xor(ns, 16, 64);
    ns += __shfl_xor(ns, 32, 64);
    if (l == 0) nred[w] = ns;
    __syncthreads();
    if (tid == 0) {
      if (j < NRED) ST_RLX(&nslab[j], nred[0] + nred[1] + nred[2] + nred[3]);
      __hip_atomic_fetch_add(&ctrB[t * CTRS], 1u, __ATOMIC_RELEASE, __HIP_MEMORY_SCOPE_AGENT);
    }
  }
}

extern "C" void kernel_launch(void* const* d_in, const int* in_sizes, int n_in,
                              void* d_out, int out_size, void* d_ws, size_t ws_size,
                              hipStream_t stream) {
  (void)in_sizes; (void)n_in; (void)out_size; (void)ws_size;
  const float* xm = (const float*)d_in[0];
  const float* xa = (const float*)d_in[1];
  const float* Wi = (const float*)d_in[2];
  const float* bi = (const float*)d_in[3];
  const float* Wr = (const float*)d_in[4];
  const float* br = (const float*)d_in[5];
  const float* Wo = (const float*)d_in[6];
  const float* bo = (const float*)d_in[7];

  char* ws = (char*)d_ws;
  f16* Wh        = (f16*)(ws + OFF_WH);
  f16* part16    = (f16*)(ws + OFF_PART);
  f16* cbuf16    = (f16*)(ws + OFF_CB);
  float* obuf    = (float*)(ws + OFF_OB);
  float* nslab   = (float*)(ws + OFF_NS);
  unsigned* ctrA = (unsigned*)(ws + OFF_CTRA);
  unsigned* ctrB = (unsigned*)(ws + OFF_CTRB);

  hipMemsetAsync(ws + ZERO_OFF, 0, ZERO_LEN, stream);
  prep_kernel<<<(97 * 8192 + 255) / 256, 256, 0, stream>>>(Wi, Wr, Wo, Wh);
  mclstm_kernel<<<NWG, 256, 0, stream>>>(xm, xa, bi, br, bo, Wh, part16, cbuf16, obuf,
                                         nslab, ctrA, ctrB, (float*)d_out);
}

// Round 6
// 49574.713 us; speedup vs baseline: 1.1723x; 1.0378x over previous
//
#include <hip/hip_runtime.h>
#include <hip/hip_fp16.h>

// MC-LSTM persistent recurrence, v6: 49 WGs (48 unit-WGs + 1 o-WG).
// NO atomic RMW barriers: per-WG single-writer flag words (release store of
// step tag), polled as one coalesced 2-line read. Single-buffered payloads
// (flag ordering proof), norm folded into the c-broadcast read.

#define TT 2048
#define NWG 49
#define NRED 48

typedef _Float16 f16;
typedef _Float16 f16x8 __attribute__((ext_vector_type(8)));
typedef _Float16 f16x4 __attribute__((ext_vector_type(4)));
typedef _Float16 f16x2 __attribute__((ext_vector_type(2)));
typedef float f32x4 __attribute__((ext_vector_type(4)));

#define LD_RLX(p)   __hip_atomic_load((p), __ATOMIC_RELAXED, __HIP_MEMORY_SCOPE_AGENT)
#define ST_RLX(p,v) __hip_atomic_store((p), (v), __ATOMIC_RELAXED, __HIP_MEMORY_SCOPE_AGENT)
#define ST_REL(p,v) __hip_atomic_store((p), (v), __ATOMIC_RELEASE, __HIP_MEMORY_SCOPE_AGENT)

static __device__ __forceinline__ void stf16(f16* p, float v) {
  f16 h = (f16)v;
  unsigned short u;
  __builtin_memcpy(&u, &h, 2);
  __hip_atomic_store((unsigned short*)p, u, __ATOMIC_RELAXED, __HIP_MEMORY_SCOPE_AGENT);
}

// ---- ws layout (bytes) ----
#define OFF_WH   0u
#define SZ_WH    (97u * 8192u * 2u)
#define OFF_PART ((OFF_WH + SZ_WH + 255u) & ~255u)   // 48 x [128][64] fp16 partials
#define SZ_PART  (48u * 8192u * 2u)
#define OFF_CB   (OFF_PART + SZ_PART)                // [128][64] fp16 c state
#define SZ_CB    (8192u * 2u)
#define OFF_OB   (OFF_CB + SZ_CB)                    // [128][64] f32 o gate
#define SZ_OB    (8192u * 4u)
#define OFF_TAGA ((OFF_OB + SZ_OB + 255u) & ~255u)   // 49 flag words (2 lines)
#define OFF_TAGB (OFF_TAGA + 256u)                   // 48 flag words (2 lines)
#define ZERO_OFF OFF_TAGA
#define ZERO_LEN 512u

__global__ void prep_kernel(const float* __restrict__ Wi, const float* __restrict__ Wr,
                            const float* __restrict__ Wo, f16* __restrict__ Wh) {
  int idx = blockIdx.x * 256 + threadIdx.x;
  if (idx >= 97 * 8192) return;
  int g = idx & 127, h = (idx >> 7) & 63, r = idx >> 13;
  float v;
  if (r < 32)      v = Wi[g * 2048 + r * 64 + h];
  else if (r < 96) v = Wr[g * 4096 + (r - 32) * 64 + h];
  else             v = Wo[g * 64 + h];
  Wh[idx] = (f16)v;
}

__launch_bounds__(256, 1)
__global__ void mclstm_kernel(const float* __restrict__ xm, const float* __restrict__ xa,
                              const float* __restrict__ bi, const float* __restrict__ br,
                              const float* __restrict__ bo, const f16* __restrict__ Wh,
                              f16* __restrict__ part16, f16* __restrict__ cbuf16,
                              float* __restrict__ obuf, unsigned* __restrict__ tagA,
                              unsigned* __restrict__ tagB, float* __restrict__ out) {
  const int j = blockIdx.x, tid = threadIdx.x;
  const int w = tid >> 6, l = tid & 63, lr = l & 15, lk = l >> 4;
  const bool isO = (j == NRED);

  __shared__ __align__(16) f16 featX[2][128][136];  // [buf][b][g]; rows 272B
  __shared__ __align__(4) f16 cL16[128][66];        // raw c (fp16)
  __shared__ float nred[4];

  // zero c state + featX[0] c-cols (t=0 path reads them)
  for (int i = tid; i < 128 * 33; i += 256) ((unsigned*)cL16)[i] = 0u;
  for (int p = tid; p < 4096; p += 256) {
    int b = p >> 5, hp = (p & 31) * 2;
    *(unsigned*)&featX[0][b][64 + hp] = 0u;
  }

  // ---- persistent weights in registers; o-WG duplicates unit 96 ----
  f16x8 Bf[2][4][4];
  float bu[2][4];
#pragma unroll
  for (int un = 0; un < 2; ++un) {
    int u = isO ? 96 : j * 2 + un;
#pragma unroll
    for (int ht = 0; ht < 4; ++ht) {
      int col = ht * 16 + lr;
      bu[un][ht] = isO ? bo[col] : ((u < 32) ? bi[u * 64 + col] : br[(u - 32) * 64 + col]);
#pragma unroll
      for (int kk = 0; kk < 4; ++kk)
        Bf[un][ht][kk] = *(const f16x8*)(Wh + (size_t)u * 8192 + col * 128 + kk * 32 + lk * 8);
    }
  }

  float4 xmr[4], xar[4];
  {
    const float4* x4 = (const float4*)xm;
    const float4* a4 = (const float4*)xa;
#pragma unroll
    for (int k = 0; k < 4; ++k) {
      int idx4 = w * 256 + k * 64 + l;
      xmr[k] = x4[idx4];
      xar[k] = a4[idx4];
    }
  }
  __syncthreads();

  // pre-loop: build featX[0] x-cols (wave-private rows) + x-GEMM(0)
  f32x4 acc[2][2][4];
#pragma unroll
  for (int k = 0; k < 4; ++k) {
    int idx4 = w * 256 + k * 64 + l;
    int row = idx4 >> 3, cq = (idx4 & 7) * 4;
    float4 v = xmr[k];
    *(f16x4*)&featX[0][row][cq] = (f16x4){(f16)v.x, (f16)v.y, (f16)v.z, (f16)v.w};
    float4 va = xar[k];
    *(f16x4*)&featX[0][row][32 + cq] = (f16x4){(f16)va.x, (f16)va.y, (f16)va.z, (f16)va.w};
  }
#pragma unroll
  for (int un = 0; un < 2; ++un)
#pragma unroll
    for (int bt = 0; bt < 2; ++bt)
#pragma unroll
      for (int ht = 0; ht < 4; ++ht) acc[un][bt][ht] = (f32x4){0.f, 0.f, 0.f, 0.f};
#pragma unroll
  for (int bt = 0; bt < 2; ++bt) {
    int row = (2 * w + bt) * 16 + lr;
    f16x8 A0 = *(const f16x8*)&featX[0][row][lk * 8];
    f16x8 A1 = *(const f16x8*)&featX[0][row][32 + lk * 8];
#pragma unroll
    for (int un = 0; un < 2; ++un)
#pragma unroll
      for (int ht = 0; ht < 4; ++ht) {
        acc[un][bt][ht] = __builtin_amdgcn_mfma_f32_16x16x32_f16(A0, Bf[un][ht][0],
                                                                 acc[un][bt][ht], 0, 0, 0);
        acc[un][bt][ht] = __builtin_amdgcn_mfma_f32_16x16x32_f16(A1, Bf[un][ht][1],
                                                                 acc[un][bt][ht], 0, 0, 0);
      }
  }

  for (int t = 0; t < TT; ++t) {
    const int buf = t & 1;

    // ---- (a) issue x[t+1] prefetch (regs stay in flight through the poll) ----
    if (t + 1 < TT) {
      const float4* x4 = (const float4*)(xm + (size_t)(t + 1) * 4096);
      const float4* a4 = (const float4*)(xa + (size_t)(t + 1) * 4096);
#pragma unroll
      for (int k = 0; k < 4; ++k) {
        int idx4 = w * 256 + k * 64 + l;
        xmr[k] = x4[idx4];
        xar[k] = a4[idx4];
      }
    }

    // ---- (b) wait for c[t] flags; read cbuf; norm; stage cn+raw c ----
    if (t > 0) {
      if (w == 0) {
        const unsigned want = (unsigned)t;
        unsigned v;
        do {
          v = (l < NRED) ? LD_RLX(&tagB[l]) : want;
        } while (__all((int)(v >= want)) == 0);
      }
      __syncthreads();

      unsigned cv[16];
#pragma unroll
      for (int k = 0; k < 16; ++k)
        cv[k] = LD_RLX((const unsigned*)cbuf16 + tid + k * 256);

      // norm (bit-identical order in every WG)
      float ns = 0.f;
#pragma unroll
      for (int k = 0; k < 16; ++k) {
        unsigned short u0 = (unsigned short)(cv[k] & 0xffffu);
        unsigned short u1 = (unsigned short)(cv[k] >> 16);
        f16 c0, c1;
        __builtin_memcpy(&c0, &u0, 2);
        __builtin_memcpy(&c1, &u1, 2);
        ns += fabsf((float)c0);
        ns += fabsf((float)c1);
      }
      ns += __shfl_xor(ns, 1, 64);
      ns += __shfl_xor(ns, 2, 64);
      ns += __shfl_xor(ns, 4, 64);
      ns += __shfl_xor(ns, 8, 64);
      ns += __shfl_xor(ns, 16, 64);
      ns += __shfl_xor(ns, 32, 64);
      if (l == 0) nred[w] = ns;
      __syncthreads();
      float nm = ((nred[0] + nred[1]) + nred[2]) + nred[3];
      const float inv = __builtin_amdgcn_rcpf(nm + 1e-5f);

#pragma unroll
      for (int k = 0; k < 16; ++k) {
        int p = tid + k * 256;
        int b = p >> 5, hp = (p & 31) * 2;
        unsigned short u0 = (unsigned short)(cv[k] & 0xffffu);
        unsigned short u1 = (unsigned short)(cv[k] >> 16);
        f16 c0, c1;
        __builtin_memcpy(&c0, &u0, 2);
        __builtin_memcpy(&c1, &u1, 2);
        *(f16x2*)&featX[buf][b][64 + hp] =
            (f16x2){(f16)((float)c0 * inv), (f16)((float)c1 * inv)};
        *(unsigned*)&cL16[b][hp] = cv[k];
      }
      __syncthreads();
    }

    // ---- (c) c-part GEMM + epilogue + partial stores ----
#pragma unroll
    for (int bt = 0; bt < 2; ++bt) {
      int row = (2 * w + bt) * 16 + lr;
      f16x8 A2 = *(const f16x8*)&featX[buf][row][64 + lk * 8];
      f16x8 A3 = *(const f16x8*)&featX[buf][row][96 + lk * 8];
#pragma unroll
      for (int un = 0; un < 2; ++un)
#pragma unroll
        for (int ht = 0; ht < 4; ++ht) {
          acc[un][bt][ht] = __builtin_amdgcn_mfma_f32_16x16x32_f16(A2, Bf[un][ht][2],
                                                                   acc[un][bt][ht], 0, 0, 0);
          acc[un][bt][ht] = __builtin_amdgcn_mfma_f32_16x16x32_f16(A3, Bf[un][ht][3],
                                                                   acc[un][bt][ht], 0, 0, 0);
        }
    }

    if (!isO) {
      const float* xmtp = xm + (size_t)t * 4096;
      float contrib[2][4][4];
#pragma unroll
      for (int bt = 0; bt < 2; ++bt)
#pragma unroll
        for (int ht = 0; ht < 4; ++ht)
#pragma unroll
          for (int rr = 0; rr < 4; ++rr) contrib[bt][ht][rr] = 0.f;
#pragma unroll
      for (int un = 0; un < 2; ++un) {
        int u = j * 2 + un;
        bool isI = (u < 32);
        int kidx = isI ? u : u - 32;
#pragma unroll
        for (int bt = 0; bt < 2; ++bt)
#pragma unroll
          for (int rr = 0; rr < 4; ++rr) {
            int b = (2 * w + bt) * 16 + lk * 4 + rr;
            float s4[4], sum = 0.f;
#pragma unroll
            for (int ht = 0; ht < 4; ++ht) {
              float z = acc[un][bt][ht][rr] + bu[un][ht];
              float sg = __builtin_amdgcn_rcpf(1.0f + __expf(-z));
              s4[ht] = sg;
              sum += sg;
            }
            float r4 = sum;
            r4 += __shfl_xor(r4, 1, 64);
            r4 += __shfl_xor(r4, 2, 64);
            r4 += __shfl_xor(r4, 4, 64);
            r4 += __shfl_xor(r4, 8, 64);
            float wr;
            if (isI) {
              wr = xmtp[b * 32 + u];
            } else {
              f16 ch = cL16[b][kidx];
              wr = (float)ch;
            }
            float sc = wr * __builtin_amdgcn_rcpf(fmaxf(r4, 1e-12f));
#pragma unroll
            for (int ht = 0; ht < 4; ++ht) contrib[bt][ht][rr] += s4[ht] * sc;
          }
      }
#pragma unroll
      for (int bt = 0; bt < 2; ++bt)
#pragma unroll
        for (int ht = 0; ht < 4; ++ht)
#pragma unroll
          for (int rr = 0; rr < 4; ++rr) {
            int b = (2 * w + bt) * 16 + lk * 4 + rr, h = ht * 16 + lr;
            stf16(&part16[j * 8192 + b * 64 + h], contrib[bt][ht][rr]);
          }
    } else {
#pragma unroll
      for (int bt = 0; bt < 2; ++bt)
#pragma unroll
        for (int ht = 0; ht < 4; ++ht)
#pragma unroll
          for (int rr = 0; rr < 4; ++rr) {
            float z = acc[0][bt][ht][rr] + bu[0][ht];
            float sg = __builtin_amdgcn_rcpf(1.0f + __expf(-z));
            int b = (2 * w + bt) * 16 + lk * 4 + rr, h = ht * 16 + lr;
            ST_RLX(&obuf[b * 64 + h], sg);
          }
    }

    // ---- (d) publish: barrier drains stores, owner flag release-store ----
    __syncthreads();
    if (tid == 0) ST_REL(&tagA[j], (unsigned)(t + 1));

    // ---- (e) overlap: build featX[t+1] x-cols + x-GEMM(t+1) ----
    if (t + 1 < TT) {
      const int nbuf = buf ^ 1;
#pragma unroll
      for (int k = 0; k < 4; ++k) {
        int idx4 = w * 256 + k * 64 + l;
        int row = idx4 >> 3, cq = (idx4 & 7) * 4;
        float4 v = xmr[k];
        *(f16x4*)&featX[nbuf][row][cq] = (f16x4){(f16)v.x, (f16)v.y, (f16)v.z, (f16)v.w};
        float4 va = xar[k];
        *(f16x4*)&featX[nbuf][row][32 + cq] =
            (f16x4){(f16)va.x, (f16)va.y, (f16)va.z, (f16)va.w};
      }
#pragma unroll
      for (int un = 0; un < 2; ++un)
#pragma unroll
        for (int bt = 0; bt < 2; ++bt)
#pragma unroll
          for (int ht = 0; ht < 4; ++ht) acc[un][bt][ht] = (f32x4){0.f, 0.f, 0.f, 0.f};
#pragma unroll
      for (int bt = 0; bt < 2; ++bt) {
        int row = (2 * w + bt) * 16 + lr;
        f16x8 A0 = *(const f16x8*)&featX[nbuf][row][lk * 8];
        f16x8 A1 = *(const f16x8*)&featX[nbuf][row][32 + lk * 8];
#pragma unroll
        for (int un = 0; un < 2; ++un)
#pragma unroll
          for (int ht = 0; ht < 4; ++ht) {
            acc[un][bt][ht] = __builtin_amdgcn_mfma_f32_16x16x32_f16(A0, Bf[un][ht][0],
                                                                     acc[un][bt][ht], 0, 0, 0);
            acc[un][bt][ht] = __builtin_amdgcn_mfma_f32_16x16x32_f16(A1, Bf[un][ht][1],
                                                                     acc[un][bt][ht], 0, 0, 0);
          }
      }
    }

    // ---- (f)/(g) reducers only: wait all partials, reduce slice, publish c ----
    if (j < NRED) {
      if (w == 0) {
        const unsigned want = (unsigned)(t + 1);
        unsigned v;
        do {
          v = (l < NWG) ? LD_RLX(&tagA[l]) : want;
        } while (__all((int)(v >= want)) == 0);
      }
      __syncthreads();

      const int e = j * 171 + tid;
      const bool act = (tid < 171 && e < 8192);
      float mn = 0.f, ov = 0.f, cn_ = 0.f;
      if (act) {
        unsigned short us[NRED];
#pragma unroll
        for (int p = 0; p < NRED; ++p)
          us[p] = __hip_atomic_load((const unsigned short*)part16 + p * 8192 + e,
                                    __ATOMIC_RELAXED, __HIP_MEMORY_SCOPE_AGENT);
#pragma unroll
        for (int p = 0; p < NRED; ++p) {
          f16 h;
          __builtin_memcpy(&h, &us[p], 2);
          mn += (float)h;
        }
        ov = LD_RLX(&obuf[e]);
        cn_ = (1.0f - ov) * mn;
        stf16(&cbuf16[e], cn_);
      }
      __syncthreads();  // drains cbuf stores of all waves
      if (tid == 0) ST_REL(&tagB[j], (unsigned)(t + 1));
      if (act) {  // off critical path: drained at a later barrier
        out[(size_t)t * 8192 + e] = ov * mn;
        out[(size_t)(TT + t) * 8192 + e] = cn_;
      }
    }
  }
}

extern "C" void kernel_launch(void* const* d_in, const int* in_sizes, int n_in,
                              void* d_out, int out_size, void* d_ws, size_t ws_size,
                              hipStream_t stream) {
  (void)in_sizes; (void)n_in; (void)out_size; (void)ws_size;
  const float* xm = (const float*)d_in[0];
  const float* xa = (const float*)d_in[1];
  const float* Wi = (const float*)d_in[2];
  const float* bi = (const float*)d_in[3];
  const float* Wr = (const float*)d_in[4];
  const float* br = (const float*)d_in[5];
  const float* Wo = (const float*)d_in[6];
  const float* bo = (const float*)d_in[7];

  char* ws = (char*)d_ws;
  f16* Wh        = (f16*)(ws + OFF_WH);
  f16* part16    = (f16*)(ws + OFF_PART);
  f16* cbuf16    = (f16*)(ws + OFF_CB);
  float* obuf    = (float*)(ws + OFF_OB);
  unsigned* tagA = (unsigned*)(ws + OFF_TAGA);
  unsigned* tagB = (unsigned*)(ws + OFF_TAGB);

  hipMemsetAsync(ws + ZERO_OFF, 0, ZERO_LEN, stream);
  prep_kernel<<<(97 * 8192 + 255) / 256, 256, 0, stream>>>(Wi, Wr, Wo, Wh);
  mclstm_kernel<<<NWG, 256, 0, stream>>>(xm, xa, bi, br, bo, Wh, part16, cbuf16, obuf,
                                         tagA, tagB, (float*)d_out);
}

// Round 7
// 45838.348 us; speedup vs baseline: 1.2678x; 1.0815x over previous
//
#include <hip/hip_runtime.h>
#include <hip/hip_fp16.h>

// MC-LSTM persistent recurrence, v7: 49 WGs (48 unit-WGs + 1 o-WG).
// v6 + ZERO cache-maintenance ops in the loop: all cross-WG traffic is
// agent-scope RELAXED (MALL-direct); flag publishes rely on __syncthreads'
// per-wave vmcnt(0) drain for ordering (no release -> no buffer_wbl2;
// no acquire -> no buffer_inv). out[] also MALL-direct so L2 stays clean.

#define TT 2048
#define NWG 49
#define NRED 48

typedef _Float16 f16;
typedef _Float16 f16x8 __attribute__((ext_vector_type(8)));
typedef _Float16 f16x4 __attribute__((ext_vector_type(4)));
typedef _Float16 f16x2 __attribute__((ext_vector_type(2)));
typedef float f32x4 __attribute__((ext_vector_type(4)));

#define LD_RLX(p)   __hip_atomic_load((p), __ATOMIC_RELAXED, __HIP_MEMORY_SCOPE_AGENT)
#define ST_RLX(p,v) __hip_atomic_store((p), (v), __ATOMIC_RELAXED, __HIP_MEMORY_SCOPE_AGENT)

static __device__ __forceinline__ void stf16(f16* p, float v) {
  f16 h = (f16)v;
  unsigned short u;
  __builtin_memcpy(&u, &h, 2);
  __hip_atomic_store((unsigned short*)p, u, __ATOMIC_RELAXED, __HIP_MEMORY_SCOPE_AGENT);
}

// ---- ws layout (bytes) ----
#define OFF_WH   0u
#define SZ_WH    (97u * 8192u * 2u)
#define OFF_PART ((OFF_WH + SZ_WH + 255u) & ~255u)   // 48 x [128][64] fp16 partials
#define SZ_PART  (48u * 8192u * 2u)
#define OFF_CB   (OFF_PART + SZ_PART)                // [128][64] fp16 c state
#define SZ_CB    (8192u * 2u)
#define OFF_OB   (OFF_CB + SZ_CB)                    // [128][64] f32 o gate
#define SZ_OB    (8192u * 4u)
#define OFF_TAGA ((OFF_OB + SZ_OB + 255u) & ~255u)   // 49 flag words (2 lines)
#define OFF_TAGB (OFF_TAGA + 256u)                   // 48 flag words (2 lines)
#define ZERO_OFF OFF_TAGA
#define ZERO_LEN 512u

__global__ void prep_kernel(const float* __restrict__ Wi, const float* __restrict__ Wr,
                            const float* __restrict__ Wo, f16* __restrict__ Wh) {
  int idx = blockIdx.x * 256 + threadIdx.x;
  if (idx >= 97 * 8192) return;
  int g = idx & 127, h = (idx >> 7) & 63, r = idx >> 13;
  float v;
  if (r < 32)      v = Wi[g * 2048 + r * 64 + h];
  else if (r < 96) v = Wr[g * 4096 + (r - 32) * 64 + h];
  else             v = Wo[g * 64 + h];
  Wh[idx] = (f16)v;
}

__launch_bounds__(256, 1)
__global__ void mclstm_kernel(const float* __restrict__ xm, const float* __restrict__ xa,
                              const float* __restrict__ bi, const float* __restrict__ br,
                              const float* __restrict__ bo, const f16* __restrict__ Wh,
                              f16* __restrict__ part16, f16* __restrict__ cbuf16,
                              float* __restrict__ obuf, unsigned* __restrict__ tagA,
                              unsigned* __restrict__ tagB, float* __restrict__ out) {
  const int j = blockIdx.x, tid = threadIdx.x;
  const int w = tid >> 6, l = tid & 63, lr = l & 15, lk = l >> 4;
  const bool isO = (j == NRED);

  __shared__ __align__(16) f16 featX[2][128][136];  // [buf][b][g]; rows 272B
  __shared__ __align__(4) f16 cL16[128][66];        // raw c (fp16)
  __shared__ float nred[4];

  // zero c state + featX[0] c-cols (t=0 path reads them)
  for (int i = tid; i < 128 * 33; i += 256) ((unsigned*)cL16)[i] = 0u;
  for (int p = tid; p < 4096; p += 256) {
    int b = p >> 5, hp = (p & 31) * 2;
    *(unsigned*)&featX[0][b][64 + hp] = 0u;
  }

  // ---- persistent weights in registers; o-WG duplicates unit 96 ----
  f16x8 Bf[2][4][4];
  float bu[2][4];
#pragma unroll
  for (int un = 0; un < 2; ++un) {
    int u = isO ? 96 : j * 2 + un;
#pragma unroll
    for (int ht = 0; ht < 4; ++ht) {
      int col = ht * 16 + lr;
      bu[un][ht] = isO ? bo[col] : ((u < 32) ? bi[u * 64 + col] : br[(u - 32) * 64 + col]);
#pragma unroll
      for (int kk = 0; kk < 4; ++kk)
        Bf[un][ht][kk] = *(const f16x8*)(Wh + (size_t)u * 8192 + col * 128 + kk * 32 + lk * 8);
    }
  }

  float4 xmr[4], xar[4];
  {
    const float4* x4 = (const float4*)xm;
    const float4* a4 = (const float4*)xa;
#pragma unroll
    for (int k = 0; k < 4; ++k) {
      int idx4 = w * 256 + k * 64 + l;
      xmr[k] = x4[idx4];
      xar[k] = a4[idx4];
    }
  }
  __syncthreads();

  // pre-loop: build featX[0] x-cols (wave-private rows) + x-GEMM(0)
  f32x4 acc[2][2][4];
#pragma unroll
  for (int k = 0; k < 4; ++k) {
    int idx4 = w * 256 + k * 64 + l;
    int row = idx4 >> 3, cq = (idx4 & 7) * 4;
    float4 v = xmr[k];
    *(f16x4*)&featX[0][row][cq] = (f16x4){(f16)v.x, (f16)v.y, (f16)v.z, (f16)v.w};
    float4 va = xar[k];
    *(f16x4*)&featX[0][row][32 + cq] = (f16x4){(f16)va.x, (f16)va.y, (f16)va.z, (f16)va.w};
  }
#pragma unroll
  for (int un = 0; un < 2; ++un)
#pragma unroll
    for (int bt = 0; bt < 2; ++bt)
#pragma unroll
      for (int ht = 0; ht < 4; ++ht) acc[un][bt][ht] = (f32x4){0.f, 0.f, 0.f, 0.f};
#pragma unroll
  for (int bt = 0; bt < 2; ++bt) {
    int row = (2 * w + bt) * 16 + lr;
    f16x8 A0 = *(const f16x8*)&featX[0][row][lk * 8];
    f16x8 A1 = *(const f16x8*)&featX[0][row][32 + lk * 8];
#pragma unroll
    for (int un = 0; un < 2; ++un)
#pragma unroll
      for (int ht = 0; ht < 4; ++ht) {
        acc[un][bt][ht] = __builtin_amdgcn_mfma_f32_16x16x32_f16(A0, Bf[un][ht][0],
                                                                 acc[un][bt][ht], 0, 0, 0);
        acc[un][bt][ht] = __builtin_amdgcn_mfma_f32_16x16x32_f16(A1, Bf[un][ht][1],
                                                                 acc[un][bt][ht], 0, 0, 0);
      }
  }

  for (int t = 0; t < TT; ++t) {
    const int buf = t & 1;

    // ---- (a) issue x[t+1] prefetch (regs stay in flight through the poll) ----
    if (t + 1 < TT) {
      const float4* x4 = (const float4*)(xm + (size_t)(t + 1) * 4096);
      const float4* a4 = (const float4*)(xa + (size_t)(t + 1) * 4096);
#pragma unroll
      for (int k = 0; k < 4; ++k) {
        int idx4 = w * 256 + k * 64 + l;
        xmr[k] = x4[idx4];
        xar[k] = a4[idx4];
      }
    }

    // ---- (b) wait for c[t] flags; read cbuf; norm; stage cn+raw c ----
    if (t > 0) {
      if (w == 0) {
        const unsigned want = (unsigned)t;
        unsigned v;
        do {
          v = (l < NRED) ? LD_RLX(&tagB[l]) : want;
        } while (__all((int)(v >= want)) == 0);
      }
      __syncthreads();

      unsigned cv[16];
#pragma unroll
      for (int k = 0; k < 16; ++k)
        cv[k] = LD_RLX((const unsigned*)cbuf16 + tid + k * 256);

      // norm (bit-identical order in every WG)
      float ns = 0.f;
#pragma unroll
      for (int k = 0; k < 16; ++k) {
        unsigned short u0 = (unsigned short)(cv[k] & 0xffffu);
        unsigned short u1 = (unsigned short)(cv[k] >> 16);
        f16 c0, c1;
        __builtin_memcpy(&c0, &u0, 2);
        __builtin_memcpy(&c1, &u1, 2);
        ns += fabsf((float)c0);
        ns += fabsf((float)c1);
      }
      ns += __shfl_xor(ns, 1, 64);
      ns += __shfl_xor(ns, 2, 64);
      ns += __shfl_xor(ns, 4, 64);
      ns += __shfl_xor(ns, 8, 64);
      ns += __shfl_xor(ns, 16, 64);
      ns += __shfl_xor(ns, 32, 64);
      if (l == 0) nred[w] = ns;
      __syncthreads();
      float nm = ((nred[0] + nred[1]) + nred[2]) + nred[3];
      const float inv = __builtin_amdgcn_rcpf(nm + 1e-5f);

#pragma unroll
      for (int k = 0; k < 16; ++k) {
        int p = tid + k * 256;
        int b = p >> 5, hp = (p & 31) * 2;
        unsigned short u0 = (unsigned short)(cv[k] & 0xffffu);
        unsigned short u1 = (unsigned short)(cv[k] >> 16);
        f16 c0, c1;
        __builtin_memcpy(&c0, &u0, 2);
        __builtin_memcpy(&c1, &u1, 2);
        *(f16x2*)&featX[buf][b][64 + hp] =
            (f16x2){(f16)((float)c0 * inv), (f16)((float)c1 * inv)};
        *(unsigned*)&cL16[b][hp] = cv[k];
      }
      __syncthreads();
    }

    // ---- (c) c-part GEMM + epilogue + partial stores ----
#pragma unroll
    for (int bt = 0; bt < 2; ++bt) {
      int row = (2 * w + bt) * 16 + lr;
      f16x8 A2 = *(const f16x8*)&featX[buf][row][64 + lk * 8];
      f16x8 A3 = *(const f16x8*)&featX[buf][row][96 + lk * 8];
#pragma unroll
      for (int un = 0; un < 2; ++un)
#pragma unroll
        for (int ht = 0; ht < 4; ++ht) {
          acc[un][bt][ht] = __builtin_amdgcn_mfma_f32_16x16x32_f16(A2, Bf[un][ht][2],
                                                                   acc[un][bt][ht], 0, 0, 0);
          acc[un][bt][ht] = __builtin_amdgcn_mfma_f32_16x16x32_f16(A3, Bf[un][ht][3],
                                                                   acc[un][bt][ht], 0, 0, 0);
        }
    }

    if (!isO) {
      const float* xmtp = xm + (size_t)t * 4096;
      float contrib[2][4][4];
#pragma unroll
      for (int bt = 0; bt < 2; ++bt)
#pragma unroll
        for (int ht = 0; ht < 4; ++ht)
#pragma unroll
          for (int rr = 0; rr < 4; ++rr) contrib[bt][ht][rr] = 0.f;
#pragma unroll
      for (int un = 0; un < 2; ++un) {
        int u = j * 2 + un;
        bool isI = (u < 32);
        int kidx = isI ? u : u - 32;
#pragma unroll
        for (int bt = 0; bt < 2; ++bt)
#pragma unroll
          for (int rr = 0; rr < 4; ++rr) {
            int b = (2 * w + bt) * 16 + lk * 4 + rr;
            float s4[4], sum = 0.f;
#pragma unroll
            for (int ht = 0; ht < 4; ++ht) {
              float z = acc[un][bt][ht][rr] + bu[un][ht];
              float sg = __builtin_amdgcn_rcpf(1.0f + __expf(-z));
              s4[ht] = sg;
              sum += sg;
            }
            float r4 = sum;
            r4 += __shfl_xor(r4, 1, 64);
            r4 += __shfl_xor(r4, 2, 64);
            r4 += __shfl_xor(r4, 4, 64);
            r4 += __shfl_xor(r4, 8, 64);
            float wr;
            if (isI) {
              wr = xmtp[b * 32 + u];
            } else {
              f16 ch = cL16[b][kidx];
              wr = (float)ch;
            }
            float sc = wr * __builtin_amdgcn_rcpf(fmaxf(r4, 1e-12f));
#pragma unroll
            for (int ht = 0; ht < 4; ++ht) contrib[bt][ht][rr] += s4[ht] * sc;
          }
      }
#pragma unroll
      for (int bt = 0; bt < 2; ++bt)
#pragma unroll
        for (int ht = 0; ht < 4; ++ht)
#pragma unroll
          for (int rr = 0; rr < 4; ++rr) {
            int b = (2 * w + bt) * 16 + lk * 4 + rr, h = ht * 16 + lr;
            stf16(&part16[j * 8192 + b * 64 + h], contrib[bt][ht][rr]);
          }
    } else {
#pragma unroll
      for (int bt = 0; bt < 2; ++bt)
#pragma unroll
        for (int ht = 0; ht < 4; ++ht)
#pragma unroll
          for (int rr = 0; rr < 4; ++rr) {
            float z = acc[0][bt][ht][rr] + bu[0][ht];
            float sg = __builtin_amdgcn_rcpf(1.0f + __expf(-z));
            int b = (2 * w + bt) * 16 + lk * 4 + rr, h = ht * 16 + lr;
            ST_RLX(&obuf[b * 64 + h], sg);
          }
    }

    // ---- (d) publish: __syncthreads drains vmcnt(0) per wave -> RELAXED flag ----
    __syncthreads();
    if (tid == 0) ST_RLX(&tagA[j], (unsigned)(t + 1));

    // ---- (e) overlap: build featX[t+1] x-cols + x-GEMM(t+1) ----
    if (t + 1 < TT) {
      const int nbuf = buf ^ 1;
#pragma unroll
      for (int k = 0; k < 4; ++k) {
        int idx4 = w * 256 + k * 64 + l;
        int row = idx4 >> 3, cq = (idx4 & 7) * 4;
        float4 v = xmr[k];
        *(f16x4*)&featX[nbuf][row][cq] = (f16x4){(f16)v.x, (f16)v.y, (f16)v.z, (f16)v.w};
        float4 va = xar[k];
        *(f16x4*)&featX[nbuf][row][32 + cq] =
            (f16x4){(f16)va.x, (f16)va.y, (f16)va.z, (f16)va.w};
      }
#pragma unroll
      for (int un = 0; un < 2; ++un)
#pragma unroll
        for (int bt = 0; bt < 2; ++bt)
#pragma unroll
          for (int ht = 0; ht < 4; ++ht) acc[un][bt][ht] = (f32x4){0.f, 0.f, 0.f, 0.f};
#pragma unroll
      for (int bt = 0; bt < 2; ++bt) {
        int row = (2 * w + bt) * 16 + lr;
        f16x8 A0 = *(const f16x8*)&featX[nbuf][row][lk * 8];
        f16x8 A1 = *(const f16x8*)&featX[nbuf][row][32 + lk * 8];
#pragma unroll
        for (int un = 0; un < 2; ++un)
#pragma unroll
          for (int ht = 0; ht < 4; ++ht) {
            acc[un][bt][ht] = __builtin_amdgcn_mfma_f32_16x16x32_f16(A0, Bf[un][ht][0],
                                                                     acc[un][bt][ht], 0, 0, 0);
            acc[un][bt][ht] = __builtin_amdgcn_mfma_f32_16x16x32_f16(A1, Bf[un][ht][1],
                                                                     acc[un][bt][ht], 0, 0, 0);
          }
      }
    }

    // ---- (f)/(g) reducers only: wait all partials, reduce slice, publish c ----
    if (j < NRED) {
      if (w == 0) {
        const unsigned want = (unsigned)(t + 1);
        unsigned v;
        do {
          v = (l < NWG) ? LD_RLX(&tagA[l]) : want;
        } while (__all((int)(v >= want)) == 0);
      }
      __syncthreads();

      const int e = j * 171 + tid;
      const bool act = (tid < 171 && e < 8192);
      float mn = 0.f, ov = 0.f, cn_ = 0.f;
      if (act) {
        unsigned short us[NRED];
#pragma unroll
        for (int p = 0; p < NRED; ++p)
          us[p] = __hip_atomic_load((const unsigned short*)part16 + p * 8192 + e,
                                    __ATOMIC_RELAXED, __HIP_MEMORY_SCOPE_AGENT);
#pragma unroll
        for (int p = 0; p < NRED; ++p) {
          f16 h;
          __builtin_memcpy(&h, &us[p], 2);
          mn += (float)h;
        }
        ov = LD_RLX(&obuf[e]);
        cn_ = (1.0f - ov) * mn;
        stf16(&cbuf16[e], cn_);
      }
      __syncthreads();  // drains cbuf stores of all waves (vmcnt(0) per wave)
      if (tid == 0) ST_RLX(&tagB[j], (unsigned)(t + 1));
      if (act) {  // off critical path; MALL-direct so L2 stays clean
        ST_RLX(&out[(size_t)t * 8192 + e], ov * mn);
        ST_RLX(&out[(size_t)(TT + t) * 8192 + e], cn_);
      }
    }
  }
}

extern "C" void kernel_launch(void* const* d_in, const int* in_sizes, int n_in,
                              void* d_out, int out_size, void* d_ws, size_t ws_size,
                              hipStream_t stream) {
  (void)in_sizes; (void)n_in; (void)out_size; (void)ws_size;
  const float* xm = (const float*)d_in[0];
  const float* xa = (const float*)d_in[1];
  const float* Wi = (const float*)d_in[2];
  const float* bi = (const float*)d_in[3];
  const float* Wr = (const float*)d_in[4];
  const float* br = (const float*)d_in[5];
  const float* Wo = (const float*)d_in[6];
  const float* bo = (const float*)d_in[7];

  char* ws = (char*)d_ws;
  f16* Wh        = (f16*)(ws + OFF_WH);
  f16* part16    = (f16*)(ws + OFF_PART);
  f16* cbuf16    = (f16*)(ws + OFF_CB);
  float* obuf    = (float*)(ws + OFF_OB);
  unsigned* tagA = (unsigned*)(ws + OFF_TAGA);
  unsigned* tagB = (unsigned*)(ws + OFF_TAGB);

  hipMemsetAsync(ws + ZERO_OFF, 0, ZERO_LEN, stream);
  prep_kernel<<<(97 * 8192 + 255) / 256, 256, 0, stream>>>(Wi, Wr, Wo, Wh);
  mclstm_kernel<<<NWG, 256, 0, stream>>>(xm, xa, bi, br, bo, Wh, part16, cbuf16, obuf,
                                         tagA, tagB, (float*)d_out);
}

// Round 8
// 37164.548 us; speedup vs baseline: 1.5637x; 1.2334x over previous
//
#include <hip/hip_runtime.h>
#include <hip/hip_fp16.h>

// MC-LSTM persistent recurrence, v8: 48 symmetric WGs, NO flags.
// All cross-WG words are (fp16 value | 16-bit step tag) packed in one u32
// relaxed agent store; consumers poll the tagged data itself. o-gate computed
// in-place by reducers via VALU dot (Wo LDS-resident). Two tagged-data hops
// per step, zero shared flag lines.

#define TT 2048
#define NWG 48

typedef _Float16 f16;
typedef _Float16 f16x8 __attribute__((ext_vector_type(8)));
typedef _Float16 f16x4 __attribute__((ext_vector_type(4)));
typedef float f32x4 __attribute__((ext_vector_type(4)));

#define LD_RLX(p)   __hip_atomic_load((p), __ATOMIC_RELAXED, __HIP_MEMORY_SCOPE_AGENT)
#define ST_RLX(p,v) __hip_atomic_store((p), (v), __ATOMIC_RELAXED, __HIP_MEMORY_SCOPE_AGENT)

static __device__ __forceinline__ unsigned packf16(float v, unsigned tag) {
  f16 h = (f16)v;
  unsigned short s;
  __builtin_memcpy(&s, &h, 2);
  return ((unsigned)s << 16) | (tag & 0xffffu);
}
static __device__ __forceinline__ float unpackf16(unsigned u) {
  unsigned short s = (unsigned short)(u >> 16);
  f16 h;
  __builtin_memcpy(&h, &s, 2);
  return (float)h;
}
static __device__ __forceinline__ float f16bits(unsigned short s) {
  f16 h;
  __builtin_memcpy(&h, &s, 2);
  return (float)h;
}

// ---- ws layout (bytes) ----
#define OFF_WH   0u
#define SZ_WH    (97u * 8192u * 2u)
#define OFF_PART ((OFF_WH + SZ_WH + 255u) & ~255u)   // 48 x [128][64] tagged u32
#define SZ_PART  (48u * 8192u * 4u)
#define OFF_CB   (OFF_PART + SZ_PART)                // [128][64] tagged u32 c state
#define SZ_CB    (8192u * 4u)

__global__ void prep_kernel(const float* __restrict__ Wi, const float* __restrict__ Wr,
                            const float* __restrict__ Wo, f16* __restrict__ Wh) {
  int idx = blockIdx.x * 256 + threadIdx.x;
  if (idx >= 97 * 8192) return;
  int g = idx & 127, h = (idx >> 7) & 63, r = idx >> 13;
  float v;
  if (r < 32)      v = Wi[g * 2048 + r * 64 + h];
  else if (r < 96) v = Wr[g * 4096 + (r - 32) * 64 + h];
  else             v = Wo[g * 64 + h];
  Wh[idx] = (f16)v;
}

__launch_bounds__(256, 1)
__global__ void mclstm_kernel(const float* __restrict__ xm, const float* __restrict__ xa,
                              const float* __restrict__ bi, const float* __restrict__ br,
                              const float* __restrict__ bo, const f16* __restrict__ Wh,
                              unsigned* __restrict__ part, unsigned* __restrict__ cbuf,
                              float* __restrict__ out) {
  const int j = blockIdx.x, tid = threadIdx.x;
  const int w = tid >> 6, l = tid & 63, lr = l & 15, lk = l >> 4;

  __shared__ __align__(16) f16 featX[2][128][136];   // [buf][b][g]; rows 272B
  __shared__ unsigned short cL16[128][72];           // raw c bits (u16), padded
  __shared__ __align__(16) f16 WoL[64][128];         // Wo^T for the o-dot
  __shared__ float boS[64];
  __shared__ float nred[4];

  // zero c state + featX[0] c-cols (t=0 path reads them)
  for (int i = tid; i < 128 * 36; i += 256) ((unsigned*)cL16)[i] = 0u;
  for (int p = tid; p < 8192; p += 256) featX[0][p >> 6][64 + (p & 63)] = (f16)0.f;
  // Wo + bo into LDS
  for (int i = tid; i < 1024; i += 256)
    ((f16x8*)WoL)[i] = ((const f16x8*)(Wh + 96 * 8192))[i];
  if (tid < 64) boS[tid] = bo[tid];

  // ---- persistent weights in registers: 2 units per WG ----
  f16x8 Bf[2][4][4];
  float bu[2][4];
#pragma unroll
  for (int un = 0; un < 2; ++un) {
    int u = j * 2 + un;
#pragma unroll
    for (int ht = 0; ht < 4; ++ht) {
      int col = ht * 16 + lr;
      bu[un][ht] = (u < 32) ? bi[u * 64 + col] : br[(u - 32) * 64 + col];
#pragma unroll
      for (int kk = 0; kk < 4; ++kk)
        Bf[un][ht][kk] = *(const f16x8*)(Wh + (size_t)u * 8192 + col * 128 + kk * 32 + lk * 8);
    }
  }

  float4 xmr[4], xar[4];
  {
    const float4* x4 = (const float4*)xm;
    const float4* a4 = (const float4*)xa;
#pragma unroll
    for (int k = 0; k < 4; ++k) {
      int idx4 = w * 256 + k * 64 + l;
      xmr[k] = x4[idx4];
      xar[k] = a4[idx4];
    }
  }
  __syncthreads();

  // pre-loop: build featX[0] x-cols (wave-private rows) + x-GEMM(0)
  f32x4 acc[2][2][4];
#pragma unroll
  for (int k = 0; k < 4; ++k) {
    int idx4 = w * 256 + k * 64 + l;
    int row = idx4 >> 3, cq = (idx4 & 7) * 4;
    float4 v = xmr[k];
    *(f16x4*)&featX[0][row][cq] = (f16x4){(f16)v.x, (f16)v.y, (f16)v.z, (f16)v.w};
    float4 va = xar[k];
    *(f16x4*)&featX[0][row][32 + cq] = (f16x4){(f16)va.x, (f16)va.y, (f16)va.z, (f16)va.w};
  }
#pragma unroll
  for (int un = 0; un < 2; ++un)
#pragma unroll
    for (int bt = 0; bt < 2; ++bt)
#pragma unroll
      for (int ht = 0; ht < 4; ++ht) acc[un][bt][ht] = (f32x4){0.f, 0.f, 0.f, 0.f};
#pragma unroll
  for (int bt = 0; bt < 2; ++bt) {
    int row = (2 * w + bt) * 16 + lr;
    f16x8 A0 = *(const f16x8*)&featX[0][row][lk * 8];
    f16x8 A1 = *(const f16x8*)&featX[0][row][32 + lk * 8];
#pragma unroll
    for (int un = 0; un < 2; ++un)
#pragma unroll
      for (int ht = 0; ht < 4; ++ht) {
        acc[un][bt][ht] = __builtin_amdgcn_mfma_f32_16x16x32_f16(A0, Bf[un][ht][0],
                                                                 acc[un][bt][ht], 0, 0, 0);
        acc[un][bt][ht] = __builtin_amdgcn_mfma_f32_16x16x32_f16(A1, Bf[un][ht][1],
                                                                 acc[un][bt][ht], 0, 0, 0);
      }
  }

  for (int t = 0; t < TT; ++t) {
    const int buf = t & 1;

    // ---- (a) issue x[t+1] prefetch ----
    if (t + 1 < TT) {
      const float4* x4 = (const float4*)(xm + (size_t)(t + 1) * 4096);
      const float4* a4 = (const float4*)(xa + (size_t)(t + 1) * 4096);
#pragma unroll
      for (int k = 0; k < 4; ++k) {
        int idx4 = w * 256 + k * 64 + l;
        xmr[k] = x4[idx4];
        xar[k] = a4[idx4];
      }
    }

    // ---- (b) poll tagged c[t] directly; norm; stage cn + raw c ----
    if (t > 0) {
      const unsigned wantc = (unsigned)t & 0xffffu;
      unsigned cv[32];
      for (;;) {
#pragma unroll
        for (int k = 0; k < 32; ++k)
          cv[k] = LD_RLX(cbuf + tid + k * 256);
        unsigned m = 0;
#pragma unroll
        for (int k = 0; k < 32; ++k) m |= (cv[k] ^ wantc) & 0xffffu;
        if (m == 0) break;
        __builtin_amdgcn_s_sleep(2);
      }

      // norm (each cell counted once across WG; identical total in every WG)
      float ns = 0.f;
#pragma unroll
      for (int k = 0; k < 32; ++k) ns += fabsf(unpackf16(cv[k]));
      ns += __shfl_xor(ns, 1, 64);
      ns += __shfl_xor(ns, 2, 64);
      ns += __shfl_xor(ns, 4, 64);
      ns += __shfl_xor(ns, 8, 64);
      ns += __shfl_xor(ns, 16, 64);
      ns += __shfl_xor(ns, 32, 64);
      if (l == 0) nred[w] = ns;
      __syncthreads();
      float nm = ((nred[0] + nred[1]) + nred[2]) + nred[3];
      const float inv = __builtin_amdgcn_rcpf(nm + 1e-5f);

#pragma unroll
      for (int k = 0; k < 32; ++k) {
        int p = tid + k * 256;
        int b = p >> 6, h = p & 63;
        float cval = unpackf16(cv[k]);
        featX[buf][b][64 + h] = (f16)(cval * inv);
        cL16[b][h] = (unsigned short)(cv[k] >> 16);
      }
      __syncthreads();
    }

    // ---- (c) c-part GEMM + epilogue + tagged partial stores ----
#pragma unroll
    for (int bt = 0; bt < 2; ++bt) {
      int row = (2 * w + bt) * 16 + lr;
      f16x8 A2 = *(const f16x8*)&featX[buf][row][64 + lk * 8];
      f16x8 A3 = *(const f16x8*)&featX[buf][row][96 + lk * 8];
#pragma unroll
      for (int un = 0; un < 2; ++un)
#pragma unroll
        for (int ht = 0; ht < 4; ++ht) {
          acc[un][bt][ht] = __builtin_amdgcn_mfma_f32_16x16x32_f16(A2, Bf[un][ht][2],
                                                                   acc[un][bt][ht], 0, 0, 0);
          acc[un][bt][ht] = __builtin_amdgcn_mfma_f32_16x16x32_f16(A3, Bf[un][ht][3],
                                                                   acc[un][bt][ht], 0, 0, 0);
        }
    }

    {
      const float* xmtp = xm + (size_t)t * 4096;
      const unsigned tagp = (unsigned)(t + 1);
      float contrib[2][4][4];
#pragma unroll
      for (int bt = 0; bt < 2; ++bt)
#pragma unroll
        for (int ht = 0; ht < 4; ++ht)
#pragma unroll
          for (int rr = 0; rr < 4; ++rr) contrib[bt][ht][rr] = 0.f;
#pragma unroll
      for (int un = 0; un < 2; ++un) {
        int u = j * 2 + un;
        bool isI = (u < 32);
        int kidx = isI ? u : u - 32;
#pragma unroll
        for (int bt = 0; bt < 2; ++bt)
#pragma unroll
          for (int rr = 0; rr < 4; ++rr) {
            int b = (2 * w + bt) * 16 + lk * 4 + rr;
            float s4[4], sum = 0.f;
#pragma unroll
            for (int ht = 0; ht < 4; ++ht) {
              float z = acc[un][bt][ht][rr] + bu[un][ht];
              float sg = __builtin_amdgcn_rcpf(1.0f + __expf(-z));
              s4[ht] = sg;
              sum += sg;
            }
            float r4 = sum;
            r4 += __shfl_xor(r4, 1, 64);
            r4 += __shfl_xor(r4, 2, 64);
            r4 += __shfl_xor(r4, 4, 64);
            r4 += __shfl_xor(r4, 8, 64);
            float wr = isI ? xmtp[b * 32 + u] : f16bits(cL16[b][kidx]);
            float sc = wr * __builtin_amdgcn_rcpf(fmaxf(r4, 1e-12f));
#pragma unroll
            for (int ht = 0; ht < 4; ++ht) contrib[bt][ht][rr] += s4[ht] * sc;
          }
      }
#pragma unroll
      for (int bt = 0; bt < 2; ++bt)
#pragma unroll
        for (int ht = 0; ht < 4; ++ht)
#pragma unroll
          for (int rr = 0; rr < 4; ++rr) {
            int b = (2 * w + bt) * 16 + lk * 4 + rr, h = ht * 16 + lr;
            ST_RLX(&part[j * 8192 + b * 64 + h], packf16(contrib[bt][ht][rr], tagp));
          }
    }

    // ---- (e) overlap: build featX[t+1] x-cols + x-GEMM(t+1) while parts land ----
    if (t + 1 < TT) {
      const int nbuf = buf ^ 1;
#pragma unroll
      for (int k = 0; k < 4; ++k) {
        int idx4 = w * 256 + k * 64 + l;
        int row = idx4 >> 3, cq = (idx4 & 7) * 4;
        float4 v = xmr[k];
        *(f16x4*)&featX[nbuf][row][cq] = (f16x4){(f16)v.x, (f16)v.y, (f16)v.z, (f16)v.w};
        float4 va = xar[k];
        *(f16x4*)&featX[nbuf][row][32 + cq] =
            (f16x4){(f16)va.x, (f16)va.y, (f16)va.z, (f16)va.w};
      }
#pragma unroll
      for (int un = 0; un < 2; ++un)
#pragma unroll
        for (int bt = 0; bt < 2; ++bt)
#pragma unroll
          for (int ht = 0; ht < 4; ++ht) acc[un][bt][ht] = (f32x4){0.f, 0.f, 0.f, 0.f};
#pragma unroll
      for (int bt = 0; bt < 2; ++bt) {
        int row = (2 * w + bt) * 16 + lr;
        f16x8 A0 = *(const f16x8*)&featX[nbuf][row][lk * 8];
        f16x8 A1 = *(const f16x8*)&featX[nbuf][row][32 + lk * 8];
#pragma unroll
        for (int un = 0; un < 2; ++un)
#pragma unroll
          for (int ht = 0; ht < 4; ++ht) {
            acc[un][bt][ht] = __builtin_amdgcn_mfma_f32_16x16x32_f16(A0, Bf[un][ht][0],
                                                                     acc[un][bt][ht], 0, 0, 0);
            acc[un][bt][ht] = __builtin_amdgcn_mfma_f32_16x16x32_f16(A1, Bf[un][ht][1],
                                                                     acc[un][bt][ht], 0, 0, 0);
          }
      }
    }

    // ---- (f) phase B: poll tagged partials for own slice; o-dot; publish c ----
    {
      const int e = j * 171 + tid;
      if (tid < 171 && e < 8192) {
        const unsigned wantp = (unsigned)(t + 1) & 0xffffu;
        unsigned pv[NWG];
        for (;;) {
#pragma unroll
          for (int p = 0; p < NWG; ++p) pv[p] = LD_RLX(part + p * 8192 + e);
          unsigned m = 0;
#pragma unroll
          for (int p = 0; p < NWG; ++p) m |= (pv[p] ^ wantp) & 0xffffu;
          if (m == 0) break;
          __builtin_amdgcn_s_sleep(2);
        }
        float mn = 0.f;
#pragma unroll
        for (int p = 0; p < NWG; ++p) mn += unpackf16(pv[p]);

        // o gate via VALU dot: sigma(feat[b,:] . Wo[:,h] + bo[h])
        int b = e >> 6, h = e & 63;
        const f16* frow = &featX[buf][b][0];
        const f16* wrow = &WoL[h][0];
        float z = boS[h];
#pragma unroll
        for (int q = 0; q < 16; ++q) {
          f16x8 fv = *(const f16x8*)(frow + q * 8);
          f16x8 wv = *(const f16x8*)(wrow + q * 8);
#pragma unroll
          for (int i2 = 0; i2 < 8; ++i2) z += (float)fv[i2] * (float)wv[i2];
        }
        float ov = __builtin_amdgcn_rcpf(1.0f + __expf(-z));
        float cn_ = (1.0f - ov) * mn;
        ST_RLX(&cbuf[e], packf16(cn_, (unsigned)(t + 1)));
        ST_RLX(&out[(size_t)t * 8192 + e], ov * mn);
        ST_RLX(&out[(size_t)(TT + t) * 8192 + e], cn_);
      }
    }
  }
}

extern "C" void kernel_launch(void* const* d_in, const int* in_sizes, int n_in,
                              void* d_out, int out_size, void* d_ws, size_t ws_size,
                              hipStream_t stream) {
  (void)in_sizes; (void)n_in; (void)out_size; (void)ws_size;
  const float* xm = (const float*)d_in[0];
  const float* xa = (const float*)d_in[1];
  const float* Wi = (const float*)d_in[2];
  const float* bi = (const float*)d_in[3];
  const float* Wr = (const float*)d_in[4];
  const float* br = (const float*)d_in[5];
  const float* Wo = (const float*)d_in[6];
  const float* bo = (const float*)d_in[7];

  char* ws = (char*)d_ws;
  f16* Wh        = (f16*)(ws + OFF_WH);
  unsigned* part = (unsigned*)(ws + OFF_PART);
  unsigned* cbuf = (unsigned*)(ws + OFF_CB);

  // parts must be cleared per launch (replay: stale final tag == first-step want
  // at t=2047); cbuf is collision-free (wants <= 2047, stale tag = 2048).
  hipMemsetAsync(ws + OFF_PART, 0, SZ_PART, stream);
  prep_kernel<<<(97 * 8192 + 255) / 256, 256, 0, stream>>>(Wi, Wr, Wo, Wh);
  mclstm_kernel<<<NWG, 256, 0, stream>>>(xm, xa, bi, br, bo, Wh, part, cbuf,
                                         (float*)d_out);
}